// Round 7
// baseline (280.983 us; speedup 1.0000x reference)
//
#include <hip/hip_runtime.h>
#include <hip/hip_bf16.h>
#include <math.h>

#define NTOK 32768
#define HID  1024
#define NEXP 64
#define H4   256

typedef __attribute__((ext_vector_type(8))) short bf16x8;
typedef __attribute__((ext_vector_type(8))) unsigned short u16x8;
typedef __attribute__((ext_vector_type(4))) float f32x4;

static __device__ __forceinline__ ushort f2bf(float x) {
    unsigned u = __float_as_uint(x);
    unsigned r = (u + 0x7FFFu + ((u >> 16) & 1u)) >> 16;   // RNE
    return (ushort)r;
}

// RNE-cascade 3-way split. (h, m) are BIT-IDENTICAL to the proven pred
// split; l extends it for the logits path. x = h + m + l + O(2^-27 |x|).
static __device__ __forceinline__ void split3r(float x, ushort &h, ushort &m, ushort &l) {
    h = f2bf(x);
    const float r1 = x - __uint_as_float(((unsigned)h) << 16);
    m = f2bf(r1);
    const float r2 = r1 - __uint_as_float(((unsigned)m) << 16);
    l = f2bf(r2);
}

// LDS hash for the X tile (proven rounds 2/4/5/6).
#define SWZ(row, us) ((us) ^ (((row) & 7) << 3))

// ---------------------------------------------------------------------------
// Kernel 0 (prep): weights -> FRAGMENT-ORDER global layouts (unchanged).
//   W1f[p][cg][j][piece][lane][8]  : p*16384 + cg*4096 + j*1024 + piece*512 + lane*8
//   RWf[p][cg][piece][lane][8]     : p*6144  + cg*1536 + piece*512 + lane*8
// ---------------------------------------------------------------------------
__global__ __launch_bounds__(256) void prep_kernel(
    const float* __restrict__ W1, const float* __restrict__ RW,
    ushort* __restrict__ W1f, ushort* __restrict__ RWf)
{
    if (blockIdx.x < 256) {
        const int id = blockIdx.x * 256 + threadIdx.x;
        const int c  = id >> 8;                      // 0..255 (w1 output col)
        const int k0 = (id & 255) * 4;               // 0..1020
        const float4 v = *(const float4*)(W1 + (size_t)c * HID + k0);
        const int p = k0 >> 5, quad = (k0 >> 3) & 3, kk = k0 & 7;
        const int cg = c >> 6, j = (c >> 4) & 3, l15 = c & 15;
        const int lane = quad * 16 + l15;
        const size_t base = (size_t)p * 16384 + cg * 4096 + j * 1024 + lane * 8 + kk;
        const float xs[4] = {v.x, v.y, v.z, v.w};
        ushort hv[4], lv[4];
#pragma unroll
        for (int q = 0; q < 4; q++) {
            const ushort h = f2bf(xs[q]);
            hv[q] = h;
            lv[q] = f2bf(xs[q] - __uint_as_float(((unsigned)h) << 16));
        }
        *(ushort4*)(W1f + base)       = make_ushort4(hv[0], hv[1], hv[2], hv[3]);
        *(ushort4*)(W1f + base + 512) = make_ushort4(lv[0], lv[1], lv[2], lv[3]);
    } else {
        const int e  = blockIdx.x - 256;             // expert, 0..63
        const int k0 = threadIdx.x * 4;              // 0..1020
        const float4 v = *(const float4*)(RW + (size_t)e * HID + k0);
        const int p = k0 >> 5, quad = (k0 >> 3) & 3, kk = k0 & 7;
        const int cg = e >> 4, l15 = e & 15;
        const int lane = quad * 16 + l15;
        const size_t base = (size_t)p * 6144 + cg * 1536 + lane * 8 + kk;
        const float xs[4] = {v.x, v.y, v.z, v.w};
        ushort h[4], m[4], l[4];
#pragma unroll
        for (int q = 0; q < 4; q++) split3r(xs[q], h[q], m[q], l[q]);
        *(ushort4*)(RWf + base)        = make_ushort4(h[0], h[1], h[2], h[3]);
        *(ushort4*)(RWf + base + 512)  = make_ushort4(m[0], m[1], m[2], m[3]);
        *(ushort4*)(RWf + base + 1024) = make_ushort4(l[0], l[1], l[2], l[3]);
    }
}

// ---------------------------------------------------------------------------
// Kernel 1 (v11): v10 counted-wait pipeline, re-blocked for 2 blocks/CU.
// Round-6 diagnosis: grid 256 = 1 block/CU; all 8 waves lockstep at one
// barrier -> whole CU drains each iter (MfmaUtil 34%, dur*util ≈ 32µs MFMA
// floor). v11: 64-tok x 256-thr x 4-wave blocks (wave = cg, f = 0..3),
// grid 512 = 2 INDEPENDENT barrier groups per CU -> one block's waves run
// while the other drains. Per-wave work & L2 traffic identical to v10.
// ---------------------------------------------------------------------------
template<int PH>
__device__ __forceinline__ void kstep(
    int p, int cg, int lane, int quad, int l15, int row, int kc,
    const float* __restrict__ xsrc,
    const ushort* __restrict__ RWf, const ushort* __restrict__ W1f,
    ushort (&Xh)[2][2048], ushort (&Xm)[2][2048], ushort (&Xl)[2][2048],
    bf16x8 (&rwh)[2], bf16x8 (&rwm)[2], bf16x8 (&rwl)[2],
    float4 (&xp)[2][2],
    f32x4 (&accL)[4], f32x4 (&accP)[4][4])
{
    // 1. W1(p) — needed THIS iter; oldest in vmcnt FIFO.
    const ushort* __restrict__ w1p = W1f + (size_t)p * 16384 + cg * 4096 + lane * 8;
    bf16x8 bwh[4], bwl[4];
#pragma unroll
    for (int j = 0; j < 4; ++j) {
        bwh[j] = *(const bf16x8*)(w1p + j * 1024);
        bwl[j] = *(const bf16x8*)(w1p + j * 1024 + 512);
    }
    // 2. RW(p+1) -> next register set (consumed next iter)
    {
        const ushort* __restrict__ rwp =
            RWf + (size_t)((p + 1) & 31) * 6144 + cg * 1536 + lane * 8;
        rwh[PH ^ 1] = *(const bf16x8*)(rwp);
        rwm[PH ^ 1] = *(const bf16x8*)(rwp + 512);
        rwl[PH ^ 1] = *(const bf16x8*)(rwp + 1024);
    }
    // 3. X(p+2) -> next regs (HBM; consumed next iter's staging)
    xp[PH ^ 1][0] = *(const float4*)(xsrc + (size_t)((p + 2) & 31) * 32);
    xp[PH ^ 1][1] = *(const float4*)(xsrc + (size_t)((p + 2) & 31) * 32 + 4);

    // 4. A fragments from buf[PH] (panel p) — rows f*16+l15, all 64 rows
    bf16x8 axh[4], axm[4], axl[4];
#pragma unroll
    for (int f = 0; f < 4; ++f) {
        const int ra = f * 16 + l15;
        const int ua = SWZ(ra, ra * 32 + quad * 8);
        axh[f] = *(const bf16x8*)&Xh[PH][ua];
        axm[f] = *(const bf16x8*)&Xm[PH][ua];
        axl[f] = *(const bf16x8*)&Xl[PH][ua];
    }

    // 5. stage panel p+1 (data loaded LAST iter) -> buf[PH^1]
    {
        const float xs[8] = {xp[PH][0].x, xp[PH][0].y, xp[PH][0].z, xp[PH][0].w,
                             xp[PH][1].x, xp[PH][1].y, xp[PH][1].z, xp[PH][1].w};
        u16x8 sh, sm, sl;
#pragma unroll
        for (int q = 0; q < 8; ++q) {
            ushort h, m, l;
            split3r(xs[q], h, m, l);
            sh[q] = h; sm[q] = m; sl[q] = l;
        }
        const int us = SWZ(row, row * 32 + kc * 8);
        *(u16x8*)&Xh[PH ^ 1][us] = sh;
        *(u16x8*)&Xm[PH ^ 1][us] = sm;
        *(u16x8*)&Xl[PH ^ 1][us] = sl;
    }

    // 6. logits: 6-product exact split (RW regs loaded last iter — ready)
#pragma unroll
    for (int f = 0; f < 4; ++f) {
        accL[f] = __builtin_amdgcn_mfma_f32_16x16x32_bf16(axh[f], rwh[PH], accL[f], 0, 0, 0);
        accL[f] = __builtin_amdgcn_mfma_f32_16x16x32_bf16(axm[f], rwh[PH], accL[f], 0, 0, 0);
        accL[f] = __builtin_amdgcn_mfma_f32_16x16x32_bf16(axh[f], rwm[PH], accL[f], 0, 0, 0);
        accL[f] = __builtin_amdgcn_mfma_f32_16x16x32_bf16(axl[f], rwh[PH], accL[f], 0, 0, 0);
        accL[f] = __builtin_amdgcn_mfma_f32_16x16x32_bf16(axh[f], rwl[PH], accL[f], 0, 0, 0);
        accL[f] = __builtin_amdgcn_mfma_f32_16x16x32_bf16(axm[f], rwm[PH], accL[f], 0, 0, 0);
    }
    // 7. pred: 3 products (W1 issued ~400cyc earlier — covered)
#pragma unroll
    for (int j = 0; j < 4; ++j)
#pragma unroll
        for (int f = 0; f < 4; ++f) {
            accP[f][j] = __builtin_amdgcn_mfma_f32_16x16x32_bf16(axh[f], bwh[j], accP[f][j], 0, 0, 0);
            accP[f][j] = __builtin_amdgcn_mfma_f32_16x16x32_bf16(axm[f], bwh[j], accP[f][j], 0, 0, 0);
            accP[f][j] = __builtin_amdgcn_mfma_f32_16x16x32_bf16(axh[f], bwl[j], accP[f][j], 0, 0, 0);
        }

    // 8. counted fence: drain LDS ops only; global loads stay in flight.
    asm volatile("s_waitcnt lgkmcnt(0)" ::: "memory");
    __builtin_amdgcn_s_barrier();
    __builtin_amdgcn_sched_barrier(0);
}

__global__ __launch_bounds__(256, 2) void fused_mfma(
    const float* __restrict__ X,
    const ushort* __restrict__ RWf, const ushort* __restrict__ W1f,
    const float* __restrict__ B1, const float* __restrict__ W2,
    float* __restrict__ logits, float* __restrict__ s2ws)
{
    __shared__ __align__(16) ushort Xh[2][2048], Xm[2][2048], Xl[2][2048];
    __shared__ float red[4][64];

    const int tid  = threadIdx.x;
    const int lane = tid & 63;
    const int cg   = tid >> 6;           // wave 0..3 = col group
    const int quad = lane >> 4, l15 = lane & 15;
    const int tok0 = blockIdx.x * 64;

    const int row = tid >> 2;            // 0..63 (staging row)
    const int kc  = tid & 3;             // 8-float k-chunk

    f32x4 accL[4];
    f32x4 accP[4][4];
#pragma unroll
    for (int f = 0; f < 4; f++) {
        accL[f] = (f32x4){0.f, 0.f, 0.f, 0.f};
#pragma unroll
        for (int j = 0; j < 4; j++) accP[f][j] = (f32x4){0.f, 0.f, 0.f, 0.f};
    }

    const float* __restrict__ xsrc = X + (size_t)(tok0 + row) * HID + kc * 8;

    bf16x8 rwh[2], rwm[2], rwl[2];
    float4 xp[2][2];

    // ---- prologue: stage panel 0; prefetch RW(0), X(1) ----
    {
        const float4 a0 = *(const float4*)(xsrc);
        const float4 a1 = *(const float4*)(xsrc + 4);
        const float xs[8] = {a0.x, a0.y, a0.z, a0.w, a1.x, a1.y, a1.z, a1.w};
        u16x8 sh, sm, sl;
#pragma unroll
        for (int q = 0; q < 8; ++q) {
            ushort h, m, l;
            split3r(xs[q], h, m, l);
            sh[q] = h; sm[q] = m; sl[q] = l;
        }
        const int us = SWZ(row, row * 32 + kc * 8);
        *(u16x8*)&Xh[0][us] = sh;
        *(u16x8*)&Xm[0][us] = sm;
        *(u16x8*)&Xl[0][us] = sl;
    }
    {
        const ushort* __restrict__ rwp = RWf + (size_t)cg * 1536 + lane * 8;
        rwh[0] = *(const bf16x8*)(rwp);
        rwm[0] = *(const bf16x8*)(rwp + 512);
        rwl[0] = *(const bf16x8*)(rwp + 1024);
    }
    xp[0][0] = *(const float4*)(xsrc + 32);
    xp[0][1] = *(const float4*)(xsrc + 36);
    __syncthreads();

    for (int p = 0; p < 32; p += 2) {
        kstep<0>(p,     cg, lane, quad, l15, row, kc, xsrc, RWf, W1f,
                 Xh, Xm, Xl, rwh, rwm, rwl, xp, accL, accP);
        kstep<1>(p + 1, cg, lane, quad, l15, row, kc, xsrc, RWf, W1f,
                 Xh, Xm, Xl, rwh, rwm, rwl, xp, accL, accP);
    }

    // ---- logits epilogue (C/D: row = quad*4 + r, col = l15; proven) ----
#pragma unroll
    for (int f = 0; f < 4; ++f)
#pragma unroll
        for (int r = 0; r < 4; ++r)
            logits[(size_t)(tok0 + f * 16 + quad * 4 + r) * NEXP
                   + cg * 16 + l15] = accL[f][r];

    // ---- pred epilogue: bias+ReLU+w2 dot, cross-wave reduce in LDS ----
    float w2r[4], b1r[4];
#pragma unroll
    for (int j = 0; j < 4; ++j) {
        const int col = (cg * 4 + j) * 16 + l15;
        w2r[j] = W2[col];
        b1r[j] = B1[col];
    }
#pragma unroll
    for (int f = 0; f < 4; ++f) {
#pragma unroll
        for (int r = 0; r < 4; ++r) {
            float s = 0.f;
#pragma unroll
            for (int j = 0; j < 4; ++j) {
                const float hval = accP[f][j][r] + b1r[j];
                s = fmaf(w2r[j], fmaxf(hval, 0.f), s);
            }
            s += __shfl_xor(s, 1);
            s += __shfl_xor(s, 2);
            s += __shfl_xor(s, 4);
            s += __shfl_xor(s, 8);
            if (l15 == 0)
                red[cg][f * 16 + quad * 4 + r] = s;
        }
    }
    __syncthreads();
    if (tid < 64)
        s2ws[tok0 + tid] = red[0][tid] + red[1][tid] + red[2][tid] + red[3][tid];
}

// ---------------------------------------------------------------------------
// Kernel 3: per-token routing (unchanged, proven fast)
// ---------------------------------------------------------------------------
__global__ __launch_bounds__(64) void route_kernel(
    const float* __restrict__ logits, const float* __restrict__ s2ws,
    const float* __restrict__ B2, float* __restrict__ sel,
    float* __restrict__ wts, float* __restrict__ load_sum,
    float* __restrict__ ent_sum)
{
    const int lane = threadIdx.x;
    const int tok  = blockIdx.x * 64 + lane;

    float r[64];
    const float* lr = logits + (size_t)tok * NEXP;
#pragma unroll
    for (int e4 = 0; e4 < 16; e4++) {
        float4 v = *(const float4*)(lr + e4 * 4);
        r[e4 * 4 + 0] = v.x; r[e4 * 4 + 1] = v.y;
        r[e4 * 4 + 2] = v.z; r[e4 * 4 + 3] = v.w;
    }

    float v0 = -1e30f, v1 = -1e30f, v2 = -1e30f, v3 = -1e30f;
    int   i0 = 0, i1 = 0, i2 = 0, i3 = 0;
#pragma unroll
    for (int e = 0; e < 64; e++) {
        const float v = r[e];
        if (v > v3) {
            if (v > v2) {
                if (v > v1) {
                    if (v > v0) { v3=v2;i3=i2; v2=v1;i2=i1; v1=v0;i1=i0; v0=v;i0=e; }
                    else        { v3=v2;i3=i2; v2=v1;i2=i1; v1=v;i1=e; }
                } else          { v3=v2;i3=i2; v2=v;i2=e; }
            } else              { v3=v;i3=e; }
        }
    }

    const float s2 = s2ws[tok] + B2[0];
    const bool k4 = (s2 > 0.f);

    float w0, w1v, w2v, w3v;
    int   s1i, s2i, s3i;
    if (k4) {
        const float e0 = expf(v0 - v0), e1 = expf(v1 - v0);
        const float e2 = expf(v2 - v0), e3 = expf(v3 - v0);
        const float inv4 = 1.f / (e0 + e1 + e2 + e3);
        w0 = e0 * inv4; w1v = e1 * inv4; w2v = e2 * inv4; w3v = e3 * inv4;
        s1i = i1; s2i = i2; s3i = i3;
    } else {
        w0 = 1.f; w1v = 0.f; w2v = 0.f; w3v = 0.f;
        s1i = 0; s2i = 0; s3i = 0;
    }
    {
        float4 sv = {(float)i0, (float)s1i, (float)s2i, (float)s3i};
        float4 wv = {w0, w1v, w2v, w3v};
        *(float4*)(sel + (size_t)tok * 4) = sv;
        *(float4*)(wts + (size_t)tok * 4) = wv;
    }

    const float mx = v0;
    float S = 0.f, pz = 0.f;
#pragma unroll
    for (int e = 0; e < 64; e++) {
        const float z = r[e] - mx;
        const float t = expf(z);
        S += t; pz = fmaf(t, z, pz);
        r[e] = t;
    }
    const float inv = 1.f / S;
    float ent = logf(S) - pz * inv;

    float myload = 0.f;
#pragma unroll
    for (int e = 0; e < 64; e++) {
        float s = r[e] * inv;
        s += __shfl_xor(s, 1);
        s += __shfl_xor(s, 2);
        s += __shfl_xor(s, 4);
        s += __shfl_xor(s, 8);
        s += __shfl_xor(s, 16);
        s += __shfl_xor(s, 32);
        if (lane == e) myload = s;
    }
    atomicAdd(&load_sum[lane], myload);

    ent += __shfl_xor(ent, 1);
    ent += __shfl_xor(ent, 2);
    ent += __shfl_xor(ent, 4);
    ent += __shfl_xor(ent, 8);
    ent += __shfl_xor(ent, 16);
    ent += __shfl_xor(ent, 32);
    if (lane == 0) atomicAdd(ent_sum, ent);
}

__global__ void finalize_kernel(const float* __restrict__ load_sum,
                                const float* __restrict__ ent_sum,
                                float* __restrict__ out_scal)
{
    const int lane = threadIdx.x;
    const float le = load_sum[lane] * (1.f / (float)NTOK);
    float s = le;
#pragma unroll
    for (int o = 32; o >= 1; o >>= 1) s += __shfl_xor(s, o);
    const float mean = s * (1.f / 64.f);
    const float d = le - mean;
    float v = d * d;
#pragma unroll
    for (int o = 32; o >= 1; o >>= 1) v += __shfl_xor(v, o);
    if (lane == 0) {
        out_scal[0] = v * (1.f / 63.f);
        out_scal[1] = ent_sum[0] * (1.f / (float)NTOK);
    }
}

extern "C" void kernel_launch(void* const* d_in, const int* in_sizes, int n_in,
                              void* d_out, int out_size, void* d_ws, size_t ws_size,
                              hipStream_t stream) {
    const float* X  = (const float*)d_in[0];
    const float* RW = (const float*)d_in[1];
    const float* W1 = (const float*)d_in[2];
    const float* B1 = (const float*)d_in[3];
    const float* W2 = (const float*)d_in[4];
    const float* B2 = (const float*)d_in[5];

    float* out    = (float*)d_out;
    float* logits = out;
    float* sel    = out + (size_t)NTOK * NEXP;
    float* wts    = sel + (size_t)NTOK * 4;
    float* scal   = wts + (size_t)NTOK * 4;

    float* s2ws     = (float*)d_ws;                       // [32768] (fully written)
    float* load_sum = s2ws + NTOK;                        // [64]
    float* ent_sum  = load_sum + 64;                      // [1]
    ushort* W1f = (ushort*)(s2ws + NTOK + 256);           // 1 MB, fragment-order
    ushort* RWf = W1f + (size_t)32 * 16384;               // 384 KB, fragment-order

    hipMemsetAsync(load_sum, 0, 65 * sizeof(float), stream);

    prep_kernel<<<320, 256, 0, stream>>>(W1, RW, W1f, RWf);
    fused_mfma<<<NTOK / 64, 256, 0, stream>>>(X, RWf, W1f, B1, W2, logits, s2ws);
    route_kernel<<<NTOK / 64, 64, 0, stream>>>(logits, s2ws, B2, sel, wts, load_sum, ent_sum);
    finalize_kernel<<<1, 64, 0, stream>>>(load_sum, ent_sum, scal);
}

// Round 8
// 254.720 us; speedup vs baseline: 1.1031x; 1.1031x over previous
//
#include <hip/hip_runtime.h>
#include <hip/hip_bf16.h>
#include <math.h>

#define NTOK 32768
#define HID  1024
#define NEXP 64
#define H4   256

typedef __attribute__((ext_vector_type(8))) short bf16x8;
typedef __attribute__((ext_vector_type(8))) unsigned short u16x8;
typedef __attribute__((ext_vector_type(4))) float f32x4;

static __device__ __forceinline__ ushort f2bf(float x) {
    unsigned u = __float_as_uint(x);
    unsigned r = (u + 0x7FFFu + ((u >> 16) & 1u)) >> 16;   // RNE
    return (ushort)r;
}

// RNE-cascade 3-way split. (h, m) are BIT-IDENTICAL to the proven pred
// split; l extends it for the logits path. x = h + m + l + O(2^-27 |x|).
static __device__ __forceinline__ void split3r(float x, ushort &h, ushort &m, ushort &l) {
    h = f2bf(x);
    const float r1 = x - __uint_as_float(((unsigned)h) << 16);
    m = f2bf(r1);
    const float r2 = r1 - __uint_as_float(((unsigned)m) << 16);
    l = f2bf(r2);
}

// LDS hash for the X tile (proven rounds 2/4/5/6/7).
#define SWZ(row, us) ((us) ^ (((row) & 7) << 3))

// ---------------------------------------------------------------------------
// Kernel 0 (prep): weights -> FRAGMENT-ORDER global layouts (unchanged).
//   W1f[p][cg][j][piece][lane][8]  : p*16384 + cg*4096 + j*1024 + piece*512 + lane*8
//   RWf[p][cg][piece][lane][8]     : p*6144  + cg*1536 + piece*512 + lane*8
// ---------------------------------------------------------------------------
__global__ __launch_bounds__(256) void prep_kernel(
    const float* __restrict__ W1, const float* __restrict__ RW,
    ushort* __restrict__ W1f, ushort* __restrict__ RWf)
{
    if (blockIdx.x < 256) {
        const int id = blockIdx.x * 256 + threadIdx.x;
        const int c  = id >> 8;                      // 0..255 (w1 output col)
        const int k0 = (id & 255) * 4;               // 0..1020
        const float4 v = *(const float4*)(W1 + (size_t)c * HID + k0);
        const int p = k0 >> 5, quad = (k0 >> 3) & 3, kk = k0 & 7;
        const int cg = c >> 6, j = (c >> 4) & 3, l15 = c & 15;
        const int lane = quad * 16 + l15;
        const size_t base = (size_t)p * 16384 + cg * 4096 + j * 1024 + lane * 8 + kk;
        const float xs[4] = {v.x, v.y, v.z, v.w};
        ushort hv[4], lv[4];
#pragma unroll
        for (int q = 0; q < 4; q++) {
            const ushort h = f2bf(xs[q]);
            hv[q] = h;
            lv[q] = f2bf(xs[q] - __uint_as_float(((unsigned)h) << 16));
        }
        *(ushort4*)(W1f + base)       = make_ushort4(hv[0], hv[1], hv[2], hv[3]);
        *(ushort4*)(W1f + base + 512) = make_ushort4(lv[0], lv[1], lv[2], lv[3]);
    } else {
        const int e  = blockIdx.x - 256;             // expert, 0..63
        const int k0 = threadIdx.x * 4;              // 0..1020
        const float4 v = *(const float4*)(RW + (size_t)e * HID + k0);
        const int p = k0 >> 5, quad = (k0 >> 3) & 3, kk = k0 & 7;
        const int cg = e >> 4, l15 = e & 15;
        const int lane = quad * 16 + l15;
        const size_t base = (size_t)p * 6144 + cg * 1536 + lane * 8 + kk;
        const float xs[4] = {v.x, v.y, v.z, v.w};
        ushort h[4], m[4], l[4];
#pragma unroll
        for (int q = 0; q < 4; q++) split3r(xs[q], h[q], m[q], l[q]);
        *(ushort4*)(RWf + base)        = make_ushort4(h[0], h[1], h[2], h[3]);
        *(ushort4*)(RWf + base + 512)  = make_ushort4(m[0], m[1], m[2], m[3]);
        *(ushort4*)(RWf + base + 1024) = make_ushort4(l[0], l[1], l[2], l[3]);
    }
}

// ---------------------------------------------------------------------------
// Kernel 1 (v12): + W1 double-buffer, + route folded into epilogue.
// Round-7 diagnosis: MfmaUtil pinned ~34% across 3 schedules -> not barrier
// structure. W1 (64KB/CU-iter, 2/3 of bytes) is the ONLY operand consumed
// same-iter; L2 stream ~1140cyc > in-iter cover ~600-900cyc -> accP stalls
// every iter. v12: prefetch W1(p+1) one full iter ahead (like RW/X).
// route_kernel (512 single-wave blocks, uncoalesced 256B/lane logits
// re-read) deleted: wave 0 routes the block's 64 tokens from LDS.
// ---------------------------------------------------------------------------
template<int PH>
__device__ __forceinline__ void kstep(
    int p, int cg, int lane, int quad, int l15, int row, int kc,
    const float* __restrict__ xsrc,
    const ushort* __restrict__ RWf, const ushort* __restrict__ W1f,
    ushort (&Xh)[2][2048], ushort (&Xm)[2][2048], ushort (&Xl)[2][2048],
    bf16x8 (&rwh)[2], bf16x8 (&rwm)[2], bf16x8 (&rwl)[2],
    bf16x8 (&bwh)[2][4], bf16x8 (&bwl)[2][4],
    float4 (&xp)[2][2],
    f32x4 (&accL)[4], f32x4 (&accP)[4][4])
{
    // 1. RW(p+1) -> next register set (consumed next iter)
    {
        const ushort* __restrict__ rwp =
            RWf + (size_t)((p + 1) & 31) * 6144 + cg * 1536 + lane * 8;
        rwh[PH ^ 1] = *(const bf16x8*)(rwp);
        rwm[PH ^ 1] = *(const bf16x8*)(rwp + 512);
        rwl[PH ^ 1] = *(const bf16x8*)(rwp + 1024);
    }
    // 2. W1(p+1) -> next register set (the round-7 fix: full-iter cover)
    {
        const ushort* __restrict__ w1p =
            W1f + (size_t)((p + 1) & 31) * 16384 + cg * 4096 + lane * 8;
#pragma unroll
        for (int j = 0; j < 4; ++j) {
            bwh[PH ^ 1][j] = *(const bf16x8*)(w1p + j * 1024);
            bwl[PH ^ 1][j] = *(const bf16x8*)(w1p + j * 1024 + 512);
        }
    }
    // 3. X(p+2) -> next regs (HBM; consumed next iter's staging)
    xp[PH ^ 1][0] = *(const float4*)(xsrc + (size_t)((p + 2) & 31) * 32);
    xp[PH ^ 1][1] = *(const float4*)(xsrc + (size_t)((p + 2) & 31) * 32 + 4);

    // 4. A fragments from buf[PH] (panel p)
    bf16x8 axh[4], axm[4], axl[4];
#pragma unroll
    for (int f = 0; f < 4; ++f) {
        const int ra = f * 16 + l15;
        const int ua = SWZ(ra, ra * 32 + quad * 8);
        axh[f] = *(const bf16x8*)&Xh[PH][ua];
        axm[f] = *(const bf16x8*)&Xm[PH][ua];
        axl[f] = *(const bf16x8*)&Xl[PH][ua];
    }

    // 5. stage panel p+1 (data loaded LAST iter) -> buf[PH^1]
    {
        const float xs[8] = {xp[PH][0].x, xp[PH][0].y, xp[PH][0].z, xp[PH][0].w,
                             xp[PH][1].x, xp[PH][1].y, xp[PH][1].z, xp[PH][1].w};
        u16x8 sh, sm, sl;
#pragma unroll
        for (int q = 0; q < 8; ++q) {
            ushort h, m, l;
            split3r(xs[q], h, m, l);
            sh[q] = h; sm[q] = m; sl[q] = l;
        }
        const int us = SWZ(row, row * 32 + kc * 8);
        *(u16x8*)&Xh[PH ^ 1][us] = sh;
        *(u16x8*)&Xm[PH ^ 1][us] = sm;
        *(u16x8*)&Xl[PH ^ 1][us] = sl;
    }

    // 6. logits: 6-product exact split (all operands loaded last iter)
#pragma unroll
    for (int f = 0; f < 4; ++f) {
        accL[f] = __builtin_amdgcn_mfma_f32_16x16x32_bf16(axh[f], rwh[PH], accL[f], 0, 0, 0);
        accL[f] = __builtin_amdgcn_mfma_f32_16x16x32_bf16(axm[f], rwh[PH], accL[f], 0, 0, 0);
        accL[f] = __builtin_amdgcn_mfma_f32_16x16x32_bf16(axh[f], rwm[PH], accL[f], 0, 0, 0);
        accL[f] = __builtin_amdgcn_mfma_f32_16x16x32_bf16(axl[f], rwh[PH], accL[f], 0, 0, 0);
        accL[f] = __builtin_amdgcn_mfma_f32_16x16x32_bf16(axh[f], rwl[PH], accL[f], 0, 0, 0);
        accL[f] = __builtin_amdgcn_mfma_f32_16x16x32_bf16(axm[f], rwm[PH], accL[f], 0, 0, 0);
    }
    // 7. pred: 3 products (W1 regs loaded a full iter ago — ready)
#pragma unroll
    for (int j = 0; j < 4; ++j)
#pragma unroll
        for (int f = 0; f < 4; ++f) {
            accP[f][j] = __builtin_amdgcn_mfma_f32_16x16x32_bf16(axh[f], bwh[PH][j], accP[f][j], 0, 0, 0);
            accP[f][j] = __builtin_amdgcn_mfma_f32_16x16x32_bf16(axm[f], bwh[PH][j], accP[f][j], 0, 0, 0);
            accP[f][j] = __builtin_amdgcn_mfma_f32_16x16x32_bf16(axh[f], bwl[PH][j], accP[f][j], 0, 0, 0);
        }

    // 8. counted fence: drain LDS ops only; global loads stay in flight.
    asm volatile("s_waitcnt lgkmcnt(0)" ::: "memory");
    __builtin_amdgcn_s_barrier();
    __builtin_amdgcn_sched_barrier(0);
}

__global__ __launch_bounds__(256, 2) void fused_mfma(
    const float* __restrict__ X,
    const ushort* __restrict__ RWf, const ushort* __restrict__ W1f,
    const float* __restrict__ B1, const float* __restrict__ W2,
    const float* __restrict__ B2,
    float* __restrict__ logits, float* __restrict__ sel,
    float* __restrict__ wts, float* __restrict__ load_sum,
    float* __restrict__ ent_sum)
{
    __shared__ __align__(16) ushort Xh[2][2048], Xm[2][2048], Xl[2][2048];
    __shared__ float red[4][64];
    __shared__ float Lt[64][65];        // logits tile, pad 65: (t+e)%32 banks

    const int tid  = threadIdx.x;
    const int lane = tid & 63;
    const int cg   = tid >> 6;           // wave 0..3 = col group
    const int quad = lane >> 4, l15 = lane & 15;
    const int tok0 = blockIdx.x * 64;

    const int row = tid >> 2;            // 0..63 (staging row)
    const int kc  = tid & 3;             // 8-float k-chunk

    f32x4 accL[4];
    f32x4 accP[4][4];
#pragma unroll
    for (int f = 0; f < 4; f++) {
        accL[f] = (f32x4){0.f, 0.f, 0.f, 0.f};
#pragma unroll
        for (int j = 0; j < 4; j++) accP[f][j] = (f32x4){0.f, 0.f, 0.f, 0.f};
    }

    const float* __restrict__ xsrc = X + (size_t)(tok0 + row) * HID + kc * 8;

    bf16x8 rwh[2], rwm[2], rwl[2];
    bf16x8 bwh[2][4], bwl[2][4];
    float4 xp[2][2];

    // ---- prologue: stage panel 0; preload RW(0), W1(0); prefetch X(1) ----
    {
        const float4 a0 = *(const float4*)(xsrc);
        const float4 a1 = *(const float4*)(xsrc + 4);
        const float xs[8] = {a0.x, a0.y, a0.z, a0.w, a1.x, a1.y, a1.z, a1.w};
        u16x8 sh, sm, sl;
#pragma unroll
        for (int q = 0; q < 8; ++q) {
            ushort h, m, l;
            split3r(xs[q], h, m, l);
            sh[q] = h; sm[q] = m; sl[q] = l;
        }
        const int us = SWZ(row, row * 32 + kc * 8);
        *(u16x8*)&Xh[0][us] = sh;
        *(u16x8*)&Xm[0][us] = sm;
        *(u16x8*)&Xl[0][us] = sl;
    }
    {
        const ushort* __restrict__ rwp = RWf + (size_t)cg * 1536 + lane * 8;
        rwh[0] = *(const bf16x8*)(rwp);
        rwm[0] = *(const bf16x8*)(rwp + 512);
        rwl[0] = *(const bf16x8*)(rwp + 1024);
        const ushort* __restrict__ w1p = W1f + (size_t)cg * 4096 + lane * 8;
#pragma unroll
        for (int j = 0; j < 4; ++j) {
            bwh[0][j] = *(const bf16x8*)(w1p + j * 1024);
            bwl[0][j] = *(const bf16x8*)(w1p + j * 1024 + 512);
        }
    }
    xp[0][0] = *(const float4*)(xsrc + 32);
    xp[0][1] = *(const float4*)(xsrc + 36);
    __syncthreads();

    for (int p = 0; p < 32; p += 2) {
        kstep<0>(p,     cg, lane, quad, l15, row, kc, xsrc, RWf, W1f,
                 Xh, Xm, Xl, rwh, rwm, rwl, bwh, bwl, xp, accL, accP);
        kstep<1>(p + 1, cg, lane, quad, l15, row, kc, xsrc, RWf, W1f,
                 Xh, Xm, Xl, rwh, rwm, rwl, bwh, bwl, xp, accL, accP);
    }

    // ---- logits epilogue: global write + LDS copy for in-block routing ----
#pragma unroll
    for (int f = 0; f < 4; ++f)
#pragma unroll
        for (int r = 0; r < 4; ++r) {
            const int trow = f * 16 + quad * 4 + r;
            logits[(size_t)(tok0 + trow) * NEXP + cg * 16 + l15] = accL[f][r];
            Lt[trow][cg * 16 + l15] = accL[f][r];
        }

    // ---- pred epilogue: bias+ReLU+w2 dot, cross-wave reduce in LDS ----
    float w2r[4], b1r[4];
#pragma unroll
    for (int j = 0; j < 4; ++j) {
        const int col = (cg * 4 + j) * 16 + l15;
        w2r[j] = W2[col];
        b1r[j] = B1[col];
    }
#pragma unroll
    for (int f = 0; f < 4; ++f) {
#pragma unroll
        for (int r = 0; r < 4; ++r) {
            float s = 0.f;
#pragma unroll
            for (int j = 0; j < 4; ++j) {
                const float hval = accP[f][j][r] + b1r[j];
                s = fmaf(w2r[j], fmaxf(hval, 0.f), s);
            }
            s += __shfl_xor(s, 1);
            s += __shfl_xor(s, 2);
            s += __shfl_xor(s, 4);
            s += __shfl_xor(s, 8);
            if (l15 == 0)
                red[cg][f * 16 + quad * 4 + r] = s;
        }
    }
    __syncthreads();

    // ---- route (verbatim proven math), wave 0, token = lane ----
    if (cg == 0) {
        const int tok = tok0 + lane;

        float r[64];
#pragma unroll
        for (int e = 0; e < 64; e++) r[e] = Lt[lane][e];

        float v0 = -1e30f, v1 = -1e30f, v2 = -1e30f, v3 = -1e30f;
        int   i0 = 0, i1 = 0, i2 = 0, i3 = 0;
#pragma unroll
        for (int e = 0; e < 64; e++) {
            const float v = r[e];
            if (v > v3) {
                if (v > v2) {
                    if (v > v1) {
                        if (v > v0) { v3=v2;i3=i2; v2=v1;i2=i1; v1=v0;i1=i0; v0=v;i0=e; }
                        else        { v3=v2;i3=i2; v2=v1;i2=i1; v1=v;i1=e; }
                    } else          { v3=v2;i3=i2; v2=v;i2=e; }
                } else              { v3=v;i3=e; }
            }
        }

        const float s2 = red[0][lane] + red[1][lane] + red[2][lane]
                       + red[3][lane] + B2[0];
        const bool k4 = (s2 > 0.f);

        float w0, w1v, w2v, w3v;
        int   s1i, s2i, s3i;
        if (k4) {
            const float e0 = expf(v0 - v0), e1 = expf(v1 - v0);
            const float e2 = expf(v2 - v0), e3 = expf(v3 - v0);
            const float inv4 = 1.f / (e0 + e1 + e2 + e3);
            w0 = e0 * inv4; w1v = e1 * inv4; w2v = e2 * inv4; w3v = e3 * inv4;
            s1i = i1; s2i = i2; s3i = i3;
        } else {
            w0 = 1.f; w1v = 0.f; w2v = 0.f; w3v = 0.f;
            s1i = 0; s2i = 0; s3i = 0;
        }
        {
            float4 sv = {(float)i0, (float)s1i, (float)s2i, (float)s3i};
            float4 wv = {w0, w1v, w2v, w3v};
            *(float4*)(sel + (size_t)tok * 4) = sv;
            *(float4*)(wts + (size_t)tok * 4) = wv;
        }

        const float mx = v0;
        float S = 0.f, pz = 0.f;
#pragma unroll
        for (int e = 0; e < 64; e++) {
            const float z = r[e] - mx;
            const float t = expf(z);
            S += t; pz = fmaf(t, z, pz);
            r[e] = t;
        }
        const float inv = 1.f / S;
        float ent = logf(S) - pz * inv;

        float myload = 0.f;
#pragma unroll
        for (int e = 0; e < 64; e++) {
            float s = r[e] * inv;
            s += __shfl_xor(s, 1);
            s += __shfl_xor(s, 2);
            s += __shfl_xor(s, 4);
            s += __shfl_xor(s, 8);
            s += __shfl_xor(s, 16);
            s += __shfl_xor(s, 32);
            if (lane == e) myload = s;
        }
        atomicAdd(&load_sum[lane], myload);

        ent += __shfl_xor(ent, 1);
        ent += __shfl_xor(ent, 2);
        ent += __shfl_xor(ent, 4);
        ent += __shfl_xor(ent, 8);
        ent += __shfl_xor(ent, 16);
        ent += __shfl_xor(ent, 32);
        if (lane == 0) atomicAdd(ent_sum, ent);
    }
}

__global__ void finalize_kernel(const float* __restrict__ load_sum,
                                const float* __restrict__ ent_sum,
                                float* __restrict__ out_scal)
{
    const int lane = threadIdx.x;
    const float le = load_sum[lane] * (1.f / (float)NTOK);
    float s = le;
#pragma unroll
    for (int o = 32; o >= 1; o >>= 1) s += __shfl_xor(s, o);
    const float mean = s * (1.f / 64.f);
    const float d = le - mean;
    float v = d * d;
#pragma unroll
    for (int o = 32; o >= 1; o >>= 1) v += __shfl_xor(v, o);
    if (lane == 0) {
        out_scal[0] = v * (1.f / 63.f);
        out_scal[1] = ent_sum[0] * (1.f / (float)NTOK);
    }
}

extern "C" void kernel_launch(void* const* d_in, const int* in_sizes, int n_in,
                              void* d_out, int out_size, void* d_ws, size_t ws_size,
                              hipStream_t stream) {
    const float* X  = (const float*)d_in[0];
    const float* RW = (const float*)d_in[1];
    const float* W1 = (const float*)d_in[2];
    const float* B1 = (const float*)d_in[3];
    const float* W2 = (const float*)d_in[4];
    const float* B2 = (const float*)d_in[5];

    float* out    = (float*)d_out;
    float* logits = out;
    float* sel    = out + (size_t)NTOK * NEXP;
    float* wts    = sel + (size_t)NTOK * 4;
    float* scal   = wts + (size_t)NTOK * 4;

    float* s2ws     = (float*)d_ws;                       // [32768] (unused in v12)
    float* load_sum = s2ws + NTOK;                        // [64]
    float* ent_sum  = load_sum + 64;                      // [1]
    ushort* W1f = (ushort*)(s2ws + NTOK + 256);           // 1 MB, fragment-order
    ushort* RWf = W1f + (size_t)32 * 16384;               // 384 KB, fragment-order

    hipMemsetAsync(load_sum, 0, 65 * sizeof(float), stream);

    prep_kernel<<<320, 256, 0, stream>>>(W1, RW, W1f, RWf);
    fused_mfma<<<NTOK / 64, 256, 0, stream>>>(X, RWf, W1f, B1, W2, B2,
                                              logits, sel, wts, load_sum, ent_sum);
    finalize_kernel<<<1, 64, 0, stream>>>(load_sum, ent_sum, scal);
}